// Round 1
// baseline (155.206 us; speedup 1.0000x reference)
//
#include <hip/hip_runtime.h>

// Depthwise 3x3 conv, stride 1, pad 1.
// x: (N=16, C=384, H=128, W=128) fp32, k: (C,1,3,3) fp32, out: same as x.
// Memory-bound: ~806 MB ideal traffic -> target ~130 us at 6.3 TB/s.

#define CC 384
#define HH 128
#define WW 128
#define NN 16

__global__ __launch_bounds__(256) void dwconv3x3(const float* __restrict__ x,
                                                 const float* __restrict__ k,
                                                 float* __restrict__ out) {
    // 2 blocks of 256 threads per (n, c) plane.
    // Each thread: 4-wide (float4) x 8-tall output strip, rolling 3-row window.
    const int b    = blockIdx.x;
    const int half = b & 1;
    const int nc   = b >> 1;          // n*C + c
    const int c    = nc % CC;

    const int strip = half * 256 + (int)threadIdx.x;  // 0..511
    const int w_idx = strip & 31;                     // 0..31
    const int h_idx = strip >> 5;                     // 0..15
    const int w0 = w_idx << 2;                        // 0,4,...,124
    const int h0 = h_idx << 3;                        // 0,8,...,120

    const float* xp = x   + (size_t)nc * (HH * WW);
    float*       op = out + (size_t)nc * (HH * WW);

    // Weights: c is wave-uniform -> scalar loads.
    const float* kp = k + c * 9;
    const float w00 = kp[0], w01 = kp[1], w02 = kp[2];
    const float w10 = kp[3], w11 = kp[4], w12 = kp[5];
    const float w20 = kp[6], w21 = kp[7], w22 = kp[8];

    float r0[6], r1[6], r2[6];

    auto load_row = [&](int h, float* r) {
        if (h < 0 || h >= HH) {
            r[0] = r[1] = r[2] = r[3] = r[4] = r[5] = 0.f;
            return;
        }
        const float* p = xp + h * WW + w0;
        const float4 m = *reinterpret_cast<const float4*>(p);
        r[1] = m.x; r[2] = m.y; r[3] = m.z; r[4] = m.w;
        r[0] = (w0 > 0)       ? p[-1] : 0.f;
        r[5] = (w0 + 4 < WW)  ? p[4]  : 0.f;
    };

    load_row(h0 - 1, r0);
    load_row(h0,     r1);

    #pragma unroll
    for (int i = 0; i < 8; ++i) {
        const int h = h0 + i;
        load_row(h + 1, r2);

        float4 o;
        float* po = reinterpret_cast<float*>(&o);
        #pragma unroll
        for (int j = 0; j < 4; ++j) {
            po[j] = r0[j]     * w00 + r0[j + 1] * w01 + r0[j + 2] * w02
                  + r1[j]     * w10 + r1[j + 1] * w11 + r1[j + 2] * w12
                  + r2[j]     * w20 + r2[j + 1] * w21 + r2[j + 2] * w22;
        }
        *reinterpret_cast<float4*>(op + h * WW + w0) = o;

        #pragma unroll
        for (int t = 0; t < 6; ++t) { r0[t] = r1[t]; r1[t] = r2[t]; }
    }
}

extern "C" void kernel_launch(void* const* d_in, const int* in_sizes, int n_in,
                              void* d_out, int out_size, void* d_ws, size_t ws_size,
                              hipStream_t stream) {
    const float* x = (const float*)d_in[0];
    const float* k = (const float*)d_in[1];
    float*     out = (float*)d_out;

    const int blocks = NN * CC * 2;  // 12288
    dwconv3x3<<<blocks, 256, 0, stream>>>(x, k, out);
}